// Round 3
// baseline (36.402 us; speedup 1.0000x reference)
//
#include <hip/hip_runtime.h>
#include <math.h>

// Depthwise max-plus 5x5 correlation, pad=2, stride=1, dilation=1.
//   imgs: (8,32,256,256) f32, kernel: (32,1,5,5) f32, out same as imgs.
#define BB 8
#define CC 32
#define HH 256
#define WW 256

typedef float f32x2 __attribute__((ext_vector_type(2)));

// Thread tile: 8 rows x 8 cols (64 outputs). Block 256 threads = 64 rows x 256
// cols of one plane; 4 blocks per plane; grid = 8*32*4 = 1024.
// Packed-add trick: output rows r,r+1 consume the same input row with kernel
// rows (ky,ky-1) -> one v_pk_add_f32 (broadcast input + weight pair) covers 2
// taps. Pairs used: (ky4,ky3) and (ky2,ky1); ky0 stays scalar.
__global__ __launch_bounds__(256) void selconv_kernel(
    const float* __restrict__ imgs,
    const float* __restrict__ kern,
    float* __restrict__ out)
{
    const int t    = threadIdx.x;
    const int p    = blockIdx.x >> 2;        // plane b*C + c (uniform)
    const int blky = blockIdx.x & 3;         // 64-row chunk
    const int c    = p & (CC - 1);
    const int x    = (t & 31) * 8;           // output col base
    const int y0   = blky * 64 + (t >> 5) * 8;

    // Uniform weight load -> scalar regs.
    float w[25];
    const float* kw = kern + c * 25;
#pragma unroll
    for (int i = 0; i < 25; ++i) w[i] = kw[i];

    // Weight pairs: wp[0][k] = {w[ky=4][k], w[ky=3][k]}, wp[1][k] = {w2,w1}.
    f32x2 wp[2][5];
#pragma unroll
    for (int k = 0; k < 5; ++k) {
        wp[0][k] = f32x2{w[20 + k], w[15 + k]};
        wp[1][k] = f32x2{w[10 + k], w[5 + k]};
    }

    const float NEG = -INFINITY;
    const float* plane = imgs + (size_t)p * (HH * WW);

    float acc[8][8];
#pragma unroll
    for (int r = 0; r < 8; ++r)
#pragma unroll
        for (int j = 0; j < 8; ++j) acc[r][j] = NEG;

#pragma unroll
    for (int iyo = -2; iyo <= 9; ++iyo) {
        const int iy = y0 + iyo;
        if (iy < 0 || iy >= HH) continue;    // edge tiles only
        const float* rp = plane + iy * WW;

        // Window cols x-4 .. x+11 as 4 aligned quads (fully in or out).
        float V[16];
        {
            float4 q0 = (x >= 4) ? *reinterpret_cast<const float4*>(rp + x - 4)
                                 : make_float4(NEG, NEG, NEG, NEG);
            float4 q1 = *reinterpret_cast<const float4*>(rp + x);
            float4 q2 = *reinterpret_cast<const float4*>(rp + x + 4);
            float4 q3 = (x + 8 < WW) ? *reinterpret_cast<const float4*>(rp + x + 8)
                                     : make_float4(NEG, NEG, NEG, NEG);
            V[0]=q0.x; V[1]=q0.y; V[2]=q0.z; V[3]=q0.w;
            V[4]=q1.x; V[5]=q1.y; V[6]=q1.z; V[7]=q1.w;
            V[8]=q2.x; V[9]=q2.y; V[10]=q2.z; V[11]=q2.w;
            V[12]=q3.x; V[13]=q3.y; V[14]=q3.z; V[15]=q3.w;
        }
        // Output col x+j needs inputs x+j-2..x+j+2 = V[2+j..6+j].

#pragma unroll
        for (int kp = 0; kp < 2; ++kp) {
            const int kyA = 4 - kp * 2;          // 4 then 2
            const int kyB = kyA - 1;             // 3 then 1
            const int rA  = iyo - kyA + 2;       // compile-time
            const int rB  = iyo - kyB + 2;
            const bool vA = (rA >= 0) && (rA <= 7);
            const bool vB = (rB >= 0) && (rB <= 7);
            if (vA && vB) {
#pragma unroll
                for (int j = 0; j < 8; ++j) {
                    f32x2 m0 = f32x2{V[2+j], V[2+j]} + wp[kp][0];
                    f32x2 m1 = f32x2{V[3+j], V[3+j]} + wp[kp][1];
                    f32x2 m2 = f32x2{V[4+j], V[4+j]} + wp[kp][2];
                    f32x2 m3 = f32x2{V[5+j], V[5+j]} + wp[kp][3];
                    f32x2 m4 = f32x2{V[6+j], V[6+j]} + wp[kp][4];
                    float ax = acc[rA][j];
                    ax = fmaxf(fmaxf(ax, m0.x), m1.x);   // v_max3
                    ax = fmaxf(fmaxf(ax, m2.x), m3.x);   // v_max3
                    acc[rA][j] = fmaxf(ax, m4.x);
                    float ay = acc[rB][j];
                    ay = fmaxf(fmaxf(ay, m0.y), m1.y);
                    ay = fmaxf(fmaxf(ay, m2.y), m3.y);
                    acc[rB][j] = fmaxf(ay, m4.y);
                }
            } else if (vA || vB) {
                const int ky = vA ? kyA : kyB;   // compile-time
                const int r  = vA ? rA : rB;
#pragma unroll
                for (int j = 0; j < 8; ++j) {
                    float a = acc[r][j];
                    a = fmaxf(fmaxf(a, V[2+j] + w[ky*5+0]), V[3+j] + w[ky*5+1]);
                    a = fmaxf(fmaxf(a, V[4+j] + w[ky*5+2]), V[5+j] + w[ky*5+3]);
                    acc[r][j] = fmaxf(a, V[6+j] + w[ky*5+4]);
                }
            }
        }
        {   // ky = 0 (always scalar)
            const int r = iyo + 2;
            if (r >= 0 && r <= 7) {
#pragma unroll
                for (int j = 0; j < 8; ++j) {
                    float a = acc[r][j];
                    a = fmaxf(fmaxf(a, V[2+j] + w[0]), V[3+j] + w[1]);
                    a = fmaxf(fmaxf(a, V[4+j] + w[2]), V[5+j] + w[3]);
                    acc[r][j] = fmaxf(a, V[6+j] + w[4]);
                }
            }
        }
    }

    float* op = out + (size_t)p * (HH * WW) + y0 * WW + x;
#pragma unroll
    for (int r = 0; r < 8; ++r) {
        *reinterpret_cast<float4*>(op + r * WW) =
            make_float4(acc[r][0], acc[r][1], acc[r][2], acc[r][3]);
        *reinterpret_cast<float4*>(op + r * WW + 4) =
            make_float4(acc[r][4], acc[r][5], acc[r][6], acc[r][7]);
    }
}

extern "C" void kernel_launch(void* const* d_in, const int* in_sizes, int n_in,
                              void* d_out, int out_size, void* d_ws, size_t ws_size,
                              hipStream_t stream)
{
    const float* imgs = (const float*)d_in[0];
    const float* kern = (const float*)d_in[1];
    float* out = (float*)d_out;

    const int blocks = BB * CC * 4;   // 1024 blocks x 256 threads, 64 out/thread
    selconv_kernel<<<blocks, 256, 0, stream>>>(imgs, kern, out);
}